// Round 2
// baseline (669.222 us; speedup 1.0000x reference)
//
#include <hip/hip_runtime.h>

typedef unsigned short u16;
typedef __bf16 bf16x8 __attribute__((ext_vector_type(8)));
typedef float f32x4 __attribute__((ext_vector_type(4)));
typedef int i32x4 __attribute__((ext_vector_type(4)));
// may_alias: LDS/global buffers are accessed as u16, i32x4 and bf16x8 — without
// this, TBAA lets the compiler reorder the P-matrix u16 stores vs bf16x8 loads.
typedef i32x4 i32x4_a __attribute__((may_alias));
typedef bf16x8 bf16x8_a __attribute__((may_alias));

__device__ __forceinline__ float bf2f(u16 u) {
  union { unsigned int i; float f; } c;
  c.i = ((unsigned int)u) << 16;
  return c.f;
}
__device__ __forceinline__ u16 f2bf(float f) {
  union { float f; unsigned int i; } c;
  c.f = f;
  unsigned int r = c.i + 0x7fffu + ((c.i >> 16) & 1u);
  return (u16)(r >> 16);
}
// dual-dtype scalar load: isbf ? bf16[i] : f32[i]
__device__ __forceinline__ float gld(const void* p, int i, int isbf) {
  return isbf ? bf2f(((const u16*)p)[i]) : ((const float*)p)[i];
}
// XOR-swizzled LDS element offset (16B blocks swizzled by row low 3 bits).
__device__ __forceinline__ int sw(int row, int col, int rs) {
  return row * rs + ((((col >> 3) ^ (row & 7)) << 3) | (col & 7));
}

// ws layout (bytes):
//   0      : wqkvT  bf16 [384][128]   (98304)
//   98304  : pwT    bf16 [128][128]   (32768)
//   131072 : qkvb   f32  [384]        (1536)
//   132608 : bias16 f32  [4][64][64]  (65536)  == 16*sigmoid(cpb MLP)[h][q][k]
//   198144 : scalef f32  [4]          (16)     == exp(min(logit_scale, ln100))
//   198160 : pbf    f32  [128]        (512)
//   198672 : flag   u32  (1=bf16 inputs, 0=f32 inputs)
#define WQKVT_OFF 0
#define PWT_OFF   98304
#define QKVB_OFF  131072
#define BIAS_OFF  132608
#define SCALE_OFF 198144
#define PB_OFF    198160
#define FLAG_OFF  198672

// ---------------- dtype probe ----------------
// Reads first 512 u32 words of x. If inputs are bf16, every low half-word is a
// bf16 of ~N(0,1): exponent in [0x70,0x82] (|v| in [2^-15, 8]) essentially
// always. If inputs are f32, low half-words are mantissa bits (uniform) and
// pass ~7% of the time. Threshold at 50%.
__global__ void swin_detect(const unsigned int* __restrict__ xw,
                            unsigned int* __restrict__ flag) {
  int t = threadIdx.x;  // 64 threads
  int cnt = 0;
  for (int i = 0; i < 8; i++) {
    unsigned int w = xw[t * 8 + i];
    unsigned int lo = w & 0xffffu;
    unsigned int e = (lo >> 7) & 0xffu;
    if ((e >= 0x70u && e <= 0x82u) || lo == 0u) cnt++;
  }
  cnt += __shfl_xor(cnt, 1);
  cnt += __shfl_xor(cnt, 2);
  cnt += __shfl_xor(cnt, 4);
  cnt += __shfl_xor(cnt, 8);
  cnt += __shfl_xor(cnt, 16);
  cnt += __shfl_xor(cnt, 32);
  if (t == 0) *flag = (cnt >= 256) ? 1u : 0u;
}

// ---------------- setup: weight transposes + CPB bias table ----------------
__global__ void swin_setup(const void* __restrict__ qkv_w, const void* __restrict__ q_bias,
                           const void* __restrict__ v_bias, const void* __restrict__ ls,
                           const void* __restrict__ cpb_w1, const void* __restrict__ cpb_b1,
                           const void* __restrict__ cpb_w2, const void* __restrict__ proj_w,
                           const void* __restrict__ proj_b, char* __restrict__ ws) {
  const int b = blockIdx.x, t = threadIdx.x;
  const int isbf = (int)*(const unsigned int*)(ws + FLAG_OFF);
  u16* wqkvT = (u16*)(ws + WQKVT_OFF);
  u16* pwT = (u16*)(ws + PWT_OFF);
  float* qkvb = (float*)(ws + QKVB_OFF);
  float* bias16 = (float*)(ws + BIAS_OFF);
  float* scalef = (float*)(ws + SCALE_OFF);
  float* pbf = (float*)(ws + PB_OFF);

  if (b < 48) {            // transpose qkv_w [128][384] -> wqkvT [384][128]
    for (int k = 0; k < 4; k++) {
      int o = b * 1024 + k * 256 + t;
      wqkvT[o] = f2bf(gld(qkv_w, (o & 127) * 384 + (o >> 7), isbf));
    }
  } else if (b < 64) {     // transpose proj_w [128][128] -> pwT [128][128]
    for (int k = 0; k < 4; k++) {
      int o = (b - 48) * 1024 + k * 256 + t;
      pwT[o] = f2bf(gld(proj_w, (o & 127) * 128 + (o >> 7), isbf));
    }
  } else if (b == 64) {    // small vectors
    for (int o = t; o < 384; o += 256) {
      float v = 0.f;
      if (o < 128) v = gld(q_bias, o, isbf);
      else if (o >= 256) v = gld(v_bias, o - 256, isbf);
      qkvb[o] = v;
    }
    if (t < 128) pbf[t] = gld(proj_b, t, isbf);
    if (t < 4) scalef[t] = expf(fminf(gld(ls, t, isbf), 4.60517019f));
  } else {                 // CPB MLP -> 16*sigmoid, gathered by rel-pos index
    __shared__ float tab[225][4];
    if (t < 225) {
      int i = t / 15, j = t % 15;
      float c0, c1;
      {
        float tt = ((float)(i - 7) / 7.0f) * 8.0f;
        float s = (tt > 0.f) ? 1.f : ((tt < 0.f) ? -1.f : 0.f);
        c0 = s * log2f(fabsf(tt) + 1.f) / 3.0f;
      }
      {
        float tt = ((float)(j - 7) / 7.0f) * 8.0f;
        float s = (tt > 0.f) ? 1.f : ((tt < 0.f) ? -1.f : 0.f);
        c1 = s * log2f(fabsf(tt) + 1.f) / 3.0f;
      }
      float acc[4] = {0.f, 0.f, 0.f, 0.f};
      for (int jj = 0; jj < 512; jj++) {
        float h = c0 * gld(cpb_w1, jj, isbf) + c1 * gld(cpb_w1, 512 + jj, isbf)
                + gld(cpb_b1, jj, isbf);
        h = fmaxf(h, 0.f);
        for (int hh = 0; hh < 4; hh++) acc[hh] += h * gld(cpb_w2, jj * 4 + hh, isbf);
      }
      for (int hh = 0; hh < 4; hh++) tab[t][hh] = acc[hh];
    }
    __syncthreads();
    for (int e = t; e < 4 * 64 * 64; e += 256) {
      int h = e >> 12, q = (e >> 6) & 63, kk = e & 63;
      int dr = (q >> 3) - (kk >> 3) + 7;
      int dc = (q & 7) - (kk & 7) + 7;
      float v = tab[dr * 15 + dc][h];
      bias16[e] = 16.f / (1.f + expf(-v));
    }
  }
}

// ---------------- fused per-window kernel ----------------
// One block per window (B*256 blocks), 512 threads = 8 waves.
// Wave (mg = wid>>2, sub = wid&3):
//   GEMM1: rows 32*mg, cols 96*sub of qkv[64][384]
//   attn : rows 32*mg of head sub
//   GEMM3: rows 32*mg, cols 32*sub of out[64][128]
// LDS (u16 elements, 32768 total = 64KB), lifetime-aliased:
//   X  @0      [64][128]  (dead after GEMM1)
//   Q  @8192   [64][128]  (dead after QK^T)      } P [64][256] @0 overlays X+Q
//   K  @16384  [64][128]  (dead after QK^T)      } AO [64][128] overlays K
//   VT @24576  [128][64]  (v transposed, head-major rows)
#define X_OFF 0
#define Q_OFF 8192
#define K_OFF 16384
#define AO_OFF 16384
#define VT_OFF 24576
#define P_OFF 0

__global__ __launch_bounds__(512, 4) void swin_main(
    const void* __restrict__ x, const void* __restrict__ mask,
    const char* __restrict__ ws, void* __restrict__ out) {
  __shared__ __align__(16) u16 lds[32768];
  const f32x4 fz = {0.f, 0.f, 0.f, 0.f};

  const u16* wqkvT = (const u16*)(ws + WQKVT_OFF);
  const u16* pwT = (const u16*)(ws + PWT_OFF);
  const float* qkvb = (const float*)(ws + QKVB_OFF);
  const float* bias16 = (const float*)(ws + BIAS_OFF);
  const float* scalef = (const float*)(ws + SCALE_OFF);
  const float* pbf = (const float*)(ws + PB_OFF);
  const int isbf = (int)*(const unsigned int*)(ws + FLAG_OFF);

  const int tid = threadIdx.x;
  const int wid = tid >> 6;
  const int lane = tid & 63;
  const int ln16 = lane & 15;
  const int lq = lane >> 4;
  const int q8 = lq << 3;
  const int mg = wid >> 2;   // row half: 0/1
  const int sub = wid & 3;   // col slice / head

  const int wi = blockIdx.x;
  const int b = wi >> 8;
  const int rem = wi & 255;
  const int wy = rem >> 4, wx = rem & 15;
  const int xbase = ((b * 128 + wy * 8) * 128 + wx * 8) * 128;

  // ---- stage 1: X tile -> LDS as bf16 (coalesced) ----
  if (isbf) {
    const u16* xb = (const u16*)x;
    #pragma unroll
    for (int rep = 0; rep < 2; rep++) {
      int ch = tid + rep * 512;          // 1024 chunks of 8 elements
      int token = ch >> 4, dch = ch & 15;
      int r = token >> 3, c = token & 7;
      i32x4 v = *(const i32x4_a*)(xb + xbase + r * 16384 + c * 128 + dch * 8);
      *(i32x4_a*)(lds + sw(token, dch * 8, 128)) = v;
    }
  } else {
    const float* xf = (const float*)x;
    #pragma unroll
    for (int rep = 0; rep < 2; rep++) {
      int ch = tid + rep * 512;
      int token = ch >> 4, dch = ch & 15;
      int r = token >> 3, c = token & 7;
      const float* src = xf + xbase + r * 16384 + c * 128 + dch * 8;
      union { i32x4 v2[2]; float f[8]; } in;
      in.v2[0] = *(const i32x4_a*)(src);
      in.v2[1] = *(const i32x4_a*)(src + 4);
      union { u16 u[8]; i32x4 v; } o;
      #pragma unroll
      for (int d = 0; d < 8; d++) o.u[d] = f2bf(in.f[d]);
      *(i32x4_a*)(lds + sw(token, dch * 8, 128)) = o.v;
    }
  }
  __syncthreads();

  // ---- stage 2: GEMM1  qkv = X @ Wqkv + b ----
  f32x4 acc1[2][6];
  #pragma unroll
  for (int mt = 0; mt < 2; mt++)
    #pragma unroll
    for (int nt = 0; nt < 6; nt++) acc1[mt][nt] = fz;

  #pragma unroll
  for (int ks = 0; ks < 4; ks++) {
    bf16x8 a0 = *(const bf16x8_a*)(lds + X_OFF + sw(32 * mg + ln16, 32 * ks + q8, 128));
    bf16x8 a1 = *(const bf16x8_a*)(lds + X_OFF + sw(32 * mg + 16 + ln16, 32 * ks + q8, 128));
    bf16x8 bb[6];
    #pragma unroll
    for (int nt = 0; nt < 6; nt++)
      bb[nt] = *(const bf16x8_a*)(wqkvT + (96 * sub + 16 * nt + ln16) * 128 + 32 * ks + q8);
    #pragma unroll
    for (int nt = 0; nt < 6; nt++) {
      acc1[0][nt] = __builtin_amdgcn_mfma_f32_16x16x32_bf16(a0, bb[nt], acc1[0][nt], 0, 0, 0);
      acc1[1][nt] = __builtin_amdgcn_mfma_f32_16x16x32_bf16(a1, bb[nt], acc1[1][nt], 0, 0, 0);
    }
  }
  #pragma unroll
  for (int nt = 0; nt < 6; nt++) {
    float bv = qkvb[96 * sub + 16 * nt + ln16];
    #pragma unroll
    for (int mt = 0; mt < 2; mt++)
      #pragma unroll
      for (int r = 0; r < 4; r++) acc1[mt][nt][r] += bv;
  }
  // epilogue: per 32-col chunk -> q/k normalized rows, v transposed
  #pragma unroll
  for (int ci = 0; ci < 3; ci++) {
    int n0 = 96 * sub + 32 * ci;
    int type = n0 >> 7;              // 0=q 1=k 2=v
    int head = (n0 & 127) >> 5;
    int nt0 = 2 * ci, nt1 = nt0 + 1;
    if (type < 2) {
      int base = (type == 0) ? Q_OFF : K_OFF;
      #pragma unroll
      for (int mt = 0; mt < 2; mt++)
        #pragma unroll
        for (int r = 0; r < 4; r++) {
          float x0 = acc1[mt][nt0][r], x1 = acc1[mt][nt1][r];
          float ss = x0 * x0 + x1 * x1;
          ss += __shfl_xor(ss, 1);
          ss += __shfl_xor(ss, 2);
          ss += __shfl_xor(ss, 4);
          ss += __shfl_xor(ss, 8);
          float inv = 1.0f / fmaxf(sqrtf(ss), 1e-12f);
          int row = 32 * mg + 16 * mt + 4 * lq + r;
          lds[base + sw(row, head * 32 + ln16, 128)] = f2bf(x0 * inv);
          lds[base + sw(row, head * 32 + 16 + ln16, 128)] = f2bf(x1 * inv);
        }
    } else {
      #pragma unroll
      for (int mt = 0; mt < 2; mt++)
        #pragma unroll
        for (int r = 0; r < 4; r++) {
          int row = 32 * mg + 16 * mt + 4 * lq + r;
          lds[VT_OFF + sw(head * 32 + ln16, row, 64)] = f2bf(acc1[mt][nt0][r]);
          lds[VT_OFF + sw(head * 32 + 16 + ln16, row, 64)] = f2bf(acc1[mt][nt1][r]);
        }
    }
  }
  __syncthreads();

  // ---- stage 3: S = (q.k^T)*scale + bias + mask, softmax ----
  const int h = sub;
  const float scale = scalef[h];
  bf16x8 qf[2], kf[4];
  #pragma unroll
  for (int mt = 0; mt < 2; mt++)
    qf[mt] = *(const bf16x8_a*)(lds + Q_OFF + sw(32 * mg + 16 * mt + ln16, h * 32 + q8, 128));
  #pragma unroll
  for (int nt = 0; nt < 4; nt++)
    kf[nt] = *(const bf16x8_a*)(lds + K_OFF + sw(16 * nt + ln16, h * 32 + q8, 128));
  f32x4 S[2][4];
  #pragma unroll
  for (int mt = 0; mt < 2; mt++)
    #pragma unroll
    for (int nt = 0; nt < 4; nt++)
      S[mt][nt] = __builtin_amdgcn_mfma_f32_16x16x32_bf16(qf[mt], kf[nt], fz, 0, 0, 0);

  const float* brow = bias16 + h * 4096;
  const u16* mk16 = (const u16*)mask;
  const float* mkf = (const float*)mask;
  #pragma unroll
  for (int mt = 0; mt < 2; mt++)
    #pragma unroll
    for (int r = 0; r < 4; r++) {
      int row = 32 * mg + 16 * mt + 4 * lq + r;
      #pragma unroll
      for (int nt = 0; nt < 4; nt++) {
        int col = 16 * nt + ln16;
        int mi = rem * 4096 + row * 64 + col;
        float mval = isbf ? bf2f(mk16[mi]) : mkf[mi];
        S[mt][nt][r] = S[mt][nt][r] * scale + brow[row * 64 + col] + mval;
      }
    }
  #pragma unroll
  for (int mt = 0; mt < 2; mt++)
    #pragma unroll
    for (int r = 0; r < 4; r++) {
      float m = fmaxf(fmaxf(S[mt][0][r], S[mt][1][r]), fmaxf(S[mt][2][r], S[mt][3][r]));
      m = fmaxf(m, __shfl_xor(m, 1));
      m = fmaxf(m, __shfl_xor(m, 2));
      m = fmaxf(m, __shfl_xor(m, 4));
      m = fmaxf(m, __shfl_xor(m, 8));
      float sum = 0.f;
      #pragma unroll
      for (int nt = 0; nt < 4; nt++) {
        float p = __expf(S[mt][nt][r] - m);
        S[mt][nt][r] = p;
        sum += p;
      }
      sum += __shfl_xor(sum, 1);
      sum += __shfl_xor(sum, 2);
      sum += __shfl_xor(sum, 4);
      sum += __shfl_xor(sum, 8);
      float inv = 1.0f / sum;
      #pragma unroll
      for (int nt = 0; nt < 4; nt++) S[mt][nt][r] *= inv;
    }
  __syncthreads();  // everyone done reading Q/K before P overlays X+Q

  // ---- stage 4/5: P -> LDS, O = P @ V ----
  #pragma unroll
  for (int mt = 0; mt < 2; mt++)
    #pragma unroll
    for (int nt = 0; nt < 4; nt++)
      #pragma unroll
      for (int r = 0; r < 4; r++) {
        int row = 32 * mg + 16 * mt + 4 * lq + r;
        lds[P_OFF + sw(row, h * 64 + 16 * nt + ln16, 256)] = f2bf(S[mt][nt][r]);
      }
  __syncthreads();  // order P stores before P vector loads (and cross-wave safety)
  f32x4 O[2][2];
  O[0][0] = fz; O[0][1] = fz; O[1][0] = fz; O[1][1] = fz;
  #pragma unroll
  for (int ks = 0; ks < 2; ks++) {
    bf16x8 pf[2], vf[2];
    #pragma unroll
    for (int mt = 0; mt < 2; mt++)
      pf[mt] = *(const bf16x8_a*)(lds + P_OFF + sw(32 * mg + 16 * mt + ln16, h * 64 + 32 * ks + q8, 256));
    #pragma unroll
    for (int nt = 0; nt < 2; nt++)
      vf[nt] = *(const bf16x8_a*)(lds + VT_OFF + sw(h * 32 + 16 * nt + ln16, 32 * ks + q8, 64));
    #pragma unroll
    for (int mt = 0; mt < 2; mt++)
      #pragma unroll
      for (int nt = 0; nt < 2; nt++)
        O[mt][nt] = __builtin_amdgcn_mfma_f32_16x16x32_bf16(pf[mt], vf[nt], O[mt][nt], 0, 0, 0);
  }
  #pragma unroll
  for (int mt = 0; mt < 2; mt++)
    #pragma unroll
    for (int nt = 0; nt < 2; nt++)
      #pragma unroll
      for (int r = 0; r < 4; r++) {
        int row = 32 * mg + 16 * mt + 4 * lq + r;
        lds[AO_OFF + sw(row, h * 32 + 16 * nt + ln16, 128)] = f2bf(O[mt][nt][r]);
      }
  __syncthreads();

  // ---- stage 6: out = AO @ proj_w + proj_b ----
  f32x4 acc3[2][2];
  acc3[0][0] = fz; acc3[0][1] = fz; acc3[1][0] = fz; acc3[1][1] = fz;
  #pragma unroll
  for (int ks = 0; ks < 4; ks++) {
    bf16x8 a0 = *(const bf16x8_a*)(lds + AO_OFF + sw(32 * mg + ln16, 32 * ks + q8, 128));
    bf16x8 a1 = *(const bf16x8_a*)(lds + AO_OFF + sw(32 * mg + 16 + ln16, 32 * ks + q8, 128));
    bf16x8 b0 = *(const bf16x8_a*)(pwT + (32 * sub + ln16) * 128 + 32 * ks + q8);
    bf16x8 b1 = *(const bf16x8_a*)(pwT + (32 * sub + 16 + ln16) * 128 + 32 * ks + q8);
    acc3[0][0] = __builtin_amdgcn_mfma_f32_16x16x32_bf16(a0, b0, acc3[0][0], 0, 0, 0);
    acc3[0][1] = __builtin_amdgcn_mfma_f32_16x16x32_bf16(a0, b1, acc3[0][1], 0, 0, 0);
    acc3[1][0] = __builtin_amdgcn_mfma_f32_16x16x32_bf16(a1, b0, acc3[1][0], 0, 0, 0);
    acc3[1][1] = __builtin_amdgcn_mfma_f32_16x16x32_bf16(a1, b1, acc3[1][1], 0, 0, 0);
  }
  float pb0 = pbf[32 * sub + ln16];
  float pb1 = pbf[32 * sub + 16 + ln16];
  if (isbf) {
    u16* ob = (u16*)out;
    #pragma unroll
    for (int mt = 0; mt < 2; mt++)
      #pragma unroll
      for (int r = 0; r < 4; r++) {
        int row = 32 * mg + 16 * mt + 4 * lq + r;
        int o = xbase + (row >> 3) * 16384 + (row & 7) * 128 + 32 * sub;
        ob[o + ln16] = f2bf(acc3[mt][0][r] + pb0);
        ob[o + 16 + ln16] = f2bf(acc3[mt][1][r] + pb1);
      }
  } else {
    float* of = (float*)out;
    #pragma unroll
    for (int mt = 0; mt < 2; mt++)
      #pragma unroll
      for (int r = 0; r < 4; r++) {
        int row = 32 * mg + 16 * mt + 4 * lq + r;
        int o = xbase + (row >> 3) * 16384 + (row & 7) * 128 + 32 * sub;
        of[o + ln16] = acc3[mt][0][r] + pb0;
        of[o + 16 + ln16] = acc3[mt][1][r] + pb1;
      }
  }
}

extern "C" void kernel_launch(void* const* d_in, const int* in_sizes, int n_in,
                              void* d_out, int out_size, void* d_ws, size_t ws_size,
                              hipStream_t stream) {
  const void* x      = d_in[0];
  const void* mask   = d_in[1];
  const void* qkv_w  = d_in[2];
  const void* q_bias = d_in[3];
  const void* v_bias = d_in[4];
  const void* ls     = d_in[5];
  const void* cpb_w1 = d_in[6];
  const void* cpb_b1 = d_in[7];
  const void* cpb_w2 = d_in[8];
  const void* proj_w = d_in[9];
  const void* proj_b = d_in[10];
  const int B = in_sizes[0] / (128 * 128 * 128);

  char* ws = (char*)d_ws;
  swin_detect<<<1, 64, 0, stream>>>((const unsigned int*)x,
                                    (unsigned int*)(ws + FLAG_OFF));
  swin_setup<<<66, 256, 0, stream>>>(qkv_w, q_bias, v_bias, ls, cpb_w1, cpb_b1,
                                     cpb_w2, proj_w, proj_b, ws);
  swin_main<<<B * 256, 512, 0, stream>>>(x, mask, ws, d_out);
}

// Round 3
// 429.937 us; speedup vs baseline: 1.5566x; 1.5566x over previous
//
#include <hip/hip_runtime.h>

typedef unsigned short u16;
typedef __bf16 bf16x8 __attribute__((ext_vector_type(8)));
typedef float f32x4 __attribute__((ext_vector_type(4)));
typedef int i32x4 __attribute__((ext_vector_type(4)));
// may_alias: LDS/global buffers are accessed as u16, i32x4 and bf16x8 — without
// this, TBAA lets the compiler reorder the P-matrix u16 stores vs bf16x8 loads.
typedef i32x4 i32x4_a __attribute__((may_alias));
typedef bf16x8 bf16x8_a __attribute__((may_alias));

__device__ __forceinline__ float bf2f(u16 u) {
  union { unsigned int i; float f; } c;
  c.i = ((unsigned int)u) << 16;
  return c.f;
}
__device__ __forceinline__ u16 f2bf(float f) {
  union { float f; unsigned int i; } c;
  c.f = f;
  unsigned int r = c.i + 0x7fffu + ((c.i >> 16) & 1u);
  return (u16)(r >> 16);
}
// dual-dtype scalar load: isbf ? bf16[i] : f32[i]
__device__ __forceinline__ float gld(const void* p, int i, int isbf) {
  return isbf ? bf2f(((const u16*)p)[i]) : ((const float*)p)[i];
}
// XOR-swizzled LDS element offset (16B blocks swizzled by row low 3 bits).
__device__ __forceinline__ int sw(int row, int col, int rs) {
  return row * rs + ((((col >> 3) ^ (row & 7)) << 3) | (col & 7));
}

// ws layout (bytes):
//   0      : wqkvT  bf16 [384][128]   (98304)
//   98304  : pwT    bf16 [128][128]   (32768)
//   131072 : qkvb   f32  [384]        (1536)
//   132608 : bias16 f32  [4][64][64]  (65536)  == 16*sigmoid(cpb MLP)[h][q][k]
//   198144 : scalef f32  [4]          (16)     == exp(min(logit_scale, ln100))
//   198160 : pbf    f32  [128]        (512)
//   198672 : flag   u32  (1=bf16 inputs, 0=f32 inputs)
#define WQKVT_OFF 0
#define PWT_OFF   98304
#define QKVB_OFF  131072
#define BIAS_OFF  132608
#define SCALE_OFF 198144
#define PB_OFF    198160
#define FLAG_OFF  198672

// ---------------- dtype probe ----------------
// If inputs are bf16, every low half-word of a u32 decodes to a plausible
// N(0,1) bf16; if f32, low half-words are mantissa bits (~7% pass). 50% gate.
__global__ void swin_detect(const unsigned int* __restrict__ xw,
                            unsigned int* __restrict__ flag) {
  int t = threadIdx.x;  // 64 threads
  int cnt = 0;
  for (int i = 0; i < 8; i++) {
    unsigned int w = xw[t * 8 + i];
    unsigned int lo = w & 0xffffu;
    unsigned int e = (lo >> 7) & 0xffu;
    if ((e >= 0x70u && e <= 0x82u) || lo == 0u) cnt++;
  }
  cnt += __shfl_xor(cnt, 1);
  cnt += __shfl_xor(cnt, 2);
  cnt += __shfl_xor(cnt, 4);
  cnt += __shfl_xor(cnt, 8);
  cnt += __shfl_xor(cnt, 16);
  cnt += __shfl_xor(cnt, 32);
  if (t == 0) *flag = (cnt >= 256) ? 1u : 0u;
}

// ---------------- setup v2 ----------------
// Round-2 post-mortem: v1 took 264 us (latency-bound: 512-iter rolled loop of
// dependent scalar GLOBAL loads in the CPB MLP, plus stride-384 uncoalesced
// transpose READS). v2: MLP weights staged to LDS first (coalesced), loop runs
// from LDS broadcast; transposes do coalesced reads + scattered (non-blocking)
// writes; 258 blocks for TLP.
__global__ void swin_setup(const void* __restrict__ qkv_w, const void* __restrict__ q_bias,
                           const void* __restrict__ v_bias, const void* __restrict__ ls,
                           const void* __restrict__ cpb_w1, const void* __restrict__ cpb_b1,
                           const void* __restrict__ cpb_w2, const void* __restrict__ proj_w,
                           const void* __restrict__ proj_b, char* __restrict__ ws) {
  const int b = blockIdx.x, t = threadIdx.x;
  const int isbf = (int)*(const unsigned int*)(ws + FLAG_OFF);
  u16* wqkvT = (u16*)(ws + WQKVT_OFF);
  u16* pwT = (u16*)(ws + PWT_OFF);
  float* qkvb = (float*)(ws + QKVB_OFF);
  float* bias16 = (float*)(ws + BIAS_OFF);
  float* scalef = (float*)(ws + SCALE_OFF);
  float* pbf = (float*)(ws + PB_OFF);

  if (b < 128) {           // qkv_w row b: coalesced read, scattered write
    for (int c = t; c < 384; c += 256)
      wqkvT[c * 128 + b] = f2bf(gld(qkv_w, b * 384 + c, isbf));
  } else if (b < 256) {    // proj_w row (b-128)
    int r = b - 128;
    if (t < 128) pwT[t * 128 + r] = f2bf(gld(proj_w, r * 128 + t, isbf));
  } else if (b == 256) {   // small vectors
    for (int o = t; o < 384; o += 256) {
      float v = 0.f;
      if (o < 128) v = gld(q_bias, o, isbf);
      else if (o >= 256) v = gld(v_bias, o - 256, isbf);
      qkvb[o] = v;
    }
    if (t < 128) pbf[t] = gld(proj_b, t, isbf);
    if (t < 4) scalef[t] = expf(fminf(gld(ls, t, isbf), 4.60517019f));
  } else {                 // CPB MLP -> 16*sigmoid, gathered by rel-pos index
    __shared__ float w1[1024];   // [2][512]
    __shared__ float b1[512];
    __shared__ float w2[2048];   // [512][4]
    __shared__ float tab[225][4];
    for (int i = t; i < 1024; i += 256) w1[i] = gld(cpb_w1, i, isbf);
    for (int i = t; i < 512; i += 256) b1[i] = gld(cpb_b1, i, isbf);
    for (int i = t; i < 2048; i += 256) w2[i] = gld(cpb_w2, i, isbf);
    __syncthreads();
    if (t < 225) {
      int i = t / 15, j = t % 15;
      float c0, c1;
      {
        float tt = ((float)(i - 7) / 7.0f) * 8.0f;
        float s = (tt > 0.f) ? 1.f : ((tt < 0.f) ? -1.f : 0.f);
        c0 = s * log2f(fabsf(tt) + 1.f) / 3.0f;
      }
      {
        float tt = ((float)(j - 7) / 7.0f) * 8.0f;
        float s = (tt > 0.f) ? 1.f : ((tt < 0.f) ? -1.f : 0.f);
        c1 = s * log2f(fabsf(tt) + 1.f) / 3.0f;
      }
      float acc[4] = {0.f, 0.f, 0.f, 0.f};
      for (int jj = 0; jj < 512; jj++) {
        float h = fmaxf(c0 * w1[jj] + c1 * w1[512 + jj] + b1[jj], 0.f);
        #pragma unroll
        for (int hh = 0; hh < 4; hh++) acc[hh] += h * w2[jj * 4 + hh];
      }
      #pragma unroll
      for (int hh = 0; hh < 4; hh++) tab[t][hh] = acc[hh];
    }
    __syncthreads();
    for (int e = t; e < 4 * 64 * 64; e += 256) {
      int h = e >> 12, q = (e >> 6) & 63, kk = e & 63;
      int dr = (q >> 3) - (kk >> 3) + 7;
      int dc = (q & 7) - (kk & 7) + 7;
      float v = tab[dr * 15 + dc][h];
      bias16[e] = 16.f / (1.f + expf(-v));
    }
  }
}

// ---------------- fused per-window kernel (unchanged this round) ----------------
// One block per window (B*256 blocks), 512 threads = 8 waves.
// LDS (u16 elements, 32768 total = 64KB), lifetime-aliased.
#define X_OFF 0
#define Q_OFF 8192
#define K_OFF 16384
#define AO_OFF 16384
#define VT_OFF 24576
#define P_OFF 0

__global__ __launch_bounds__(512, 4) void swin_main(
    const void* __restrict__ x, const void* __restrict__ mask,
    const char* __restrict__ ws, void* __restrict__ out) {
  __shared__ __align__(16) u16 lds[32768];
  const f32x4 fz = {0.f, 0.f, 0.f, 0.f};

  const u16* wqkvT = (const u16*)(ws + WQKVT_OFF);
  const u16* pwT = (const u16*)(ws + PWT_OFF);
  const float* qkvb = (const float*)(ws + QKVB_OFF);
  const float* bias16 = (const float*)(ws + BIAS_OFF);
  const float* scalef = (const float*)(ws + SCALE_OFF);
  const float* pbf = (const float*)(ws + PB_OFF);
  const int isbf = (int)*(const unsigned int*)(ws + FLAG_OFF);

  const int tid = threadIdx.x;
  const int wid = tid >> 6;
  const int lane = tid & 63;
  const int ln16 = lane & 15;
  const int lq = lane >> 4;
  const int q8 = lq << 3;
  const int mg = wid >> 2;   // row half: 0/1
  const int sub = wid & 3;   // col slice / head

  const int wi = blockIdx.x;
  const int b = wi >> 8;
  const int rem = wi & 255;
  const int wy = rem >> 4, wx = rem & 15;
  const int xbase = ((b * 128 + wy * 8) * 128 + wx * 8) * 128;

  // ---- stage 1: X tile -> LDS as bf16 (coalesced) ----
  if (isbf) {
    const u16* xb = (const u16*)x;
    #pragma unroll
    for (int rep = 0; rep < 2; rep++) {
      int ch = tid + rep * 512;          // 1024 chunks of 8 elements
      int token = ch >> 4, dch = ch & 15;
      int r = token >> 3, c = token & 7;
      i32x4 v = *(const i32x4_a*)(xb + xbase + r * 16384 + c * 128 + dch * 8);
      *(i32x4_a*)(lds + sw(token, dch * 8, 128)) = v;
    }
  } else {
    const float* xf = (const float*)x;
    #pragma unroll
    for (int rep = 0; rep < 2; rep++) {
      int ch = tid + rep * 512;
      int token = ch >> 4, dch = ch & 15;
      int r = token >> 3, c = token & 7;
      const float* src = xf + xbase + r * 16384 + c * 128 + dch * 8;
      union { i32x4 v2[2]; float f[8]; } in;
      in.v2[0] = *(const i32x4_a*)(src);
      in.v2[1] = *(const i32x4_a*)(src + 4);
      union { u16 u[8]; i32x4 v; } o;
      #pragma unroll
      for (int d = 0; d < 8; d++) o.u[d] = f2bf(in.f[d]);
      *(i32x4_a*)(lds + sw(token, dch * 8, 128)) = o.v;
    }
  }
  __syncthreads();

  // ---- stage 2: GEMM1  qkv = X @ Wqkv + b ----
  f32x4 acc1[2][6];
  #pragma unroll
  for (int mt = 0; mt < 2; mt++)
    #pragma unroll
    for (int nt = 0; nt < 6; nt++) acc1[mt][nt] = fz;

  #pragma unroll
  for (int ks = 0; ks < 4; ks++) {
    bf16x8 a0 = *(const bf16x8_a*)(lds + X_OFF + sw(32 * mg + ln16, 32 * ks + q8, 128));
    bf16x8 a1 = *(const bf16x8_a*)(lds + X_OFF + sw(32 * mg + 16 + ln16, 32 * ks + q8, 128));
    bf16x8 bb[6];
    #pragma unroll
    for (int nt = 0; nt < 6; nt++)
      bb[nt] = *(const bf16x8_a*)(wqkvT + (96 * sub + 16 * nt + ln16) * 128 + 32 * ks + q8);
    #pragma unroll
    for (int nt = 0; nt < 6; nt++) {
      acc1[0][nt] = __builtin_amdgcn_mfma_f32_16x16x32_bf16(a0, bb[nt], acc1[0][nt], 0, 0, 0);
      acc1[1][nt] = __builtin_amdgcn_mfma_f32_16x16x32_bf16(a1, bb[nt], acc1[1][nt], 0, 0, 0);
    }
  }
  #pragma unroll
  for (int nt = 0; nt < 6; nt++) {
    float bv = qkvb[96 * sub + 16 * nt + ln16];
    #pragma unroll
    for (int mt = 0; mt < 2; mt++)
      #pragma unroll
      for (int r = 0; r < 4; r++) acc1[mt][nt][r] += bv;
  }
  // epilogue: per 32-col chunk -> q/k normalized rows, v transposed
  #pragma unroll
  for (int ci = 0; ci < 3; ci++) {
    int n0 = 96 * sub + 32 * ci;
    int type = n0 >> 7;              // 0=q 1=k 2=v
    int head = (n0 & 127) >> 5;
    int nt0 = 2 * ci, nt1 = nt0 + 1;
    if (type < 2) {
      int base = (type == 0) ? Q_OFF : K_OFF;
      #pragma unroll
      for (int mt = 0; mt < 2; mt++)
        #pragma unroll
        for (int r = 0; r < 4; r++) {
          float x0 = acc1[mt][nt0][r], x1 = acc1[mt][nt1][r];
          float ss = x0 * x0 + x1 * x1;
          ss += __shfl_xor(ss, 1);
          ss += __shfl_xor(ss, 2);
          ss += __shfl_xor(ss, 4);
          ss += __shfl_xor(ss, 8);
          float inv = 1.0f / fmaxf(sqrtf(ss), 1e-12f);
          int row = 32 * mg + 16 * mt + 4 * lq + r;
          lds[base + sw(row, head * 32 + ln16, 128)] = f2bf(x0 * inv);
          lds[base + sw(row, head * 32 + 16 + ln16, 128)] = f2bf(x1 * inv);
        }
    } else {
      #pragma unroll
      for (int mt = 0; mt < 2; mt++)
        #pragma unroll
        for (int r = 0; r < 4; r++) {
          int row = 32 * mg + 16 * mt + 4 * lq + r;
          lds[VT_OFF + sw(head * 32 + ln16, row, 64)] = f2bf(acc1[mt][nt0][r]);
          lds[VT_OFF + sw(head * 32 + 16 + ln16, row, 64)] = f2bf(acc1[mt][nt1][r]);
        }
    }
  }
  __syncthreads();

  // ---- stage 3: S = (q.k^T)*scale + bias + mask, softmax ----
  const int h = sub;
  const float scale = scalef[h];
  bf16x8 qf[2], kf[4];
  #pragma unroll
  for (int mt = 0; mt < 2; mt++)
    qf[mt] = *(const bf16x8_a*)(lds + Q_OFF + sw(32 * mg + 16 * mt + ln16, h * 32 + q8, 128));
  #pragma unroll
  for (int nt = 0; nt < 4; nt++)
    kf[nt] = *(const bf16x8_a*)(lds + K_OFF + sw(16 * nt + ln16, h * 32 + q8, 128));
  f32x4 S[2][4];
  #pragma unroll
  for (int mt = 0; mt < 2; mt++)
    #pragma unroll
    for (int nt = 0; nt < 4; nt++)
      S[mt][nt] = __builtin_amdgcn_mfma_f32_16x16x32_bf16(qf[mt], kf[nt], fz, 0, 0, 0);

  const float* brow = bias16 + h * 4096;
  const u16* mk16 = (const u16*)mask;
  const float* mkf = (const float*)mask;
  #pragma unroll
  for (int mt = 0; mt < 2; mt++)
    #pragma unroll
    for (int r = 0; r < 4; r++) {
      int row = 32 * mg + 16 * mt + 4 * lq + r;
      #pragma unroll
      for (int nt = 0; nt < 4; nt++) {
        int col = 16 * nt + ln16;
        int mi = rem * 4096 + row * 64 + col;
        float mval = isbf ? bf2f(mk16[mi]) : mkf[mi];
        S[mt][nt][r] = S[mt][nt][r] * scale + brow[row * 64 + col] + mval;
      }
    }
  #pragma unroll
  for (int mt = 0; mt < 2; mt++)
    #pragma unroll
    for (int r = 0; r < 4; r++) {
      float m = fmaxf(fmaxf(S[mt][0][r], S[mt][1][r]), fmaxf(S[mt][2][r], S[mt][3][r]));
      m = fmaxf(m, __shfl_xor(m, 1));
      m = fmaxf(m, __shfl_xor(m, 2));
      m = fmaxf(m, __shfl_xor(m, 4));
      m = fmaxf(m, __shfl_xor(m, 8));
      float sum = 0.f;
      #pragma unroll
      for (int nt = 0; nt < 4; nt++) {
        float p = __expf(S[mt][nt][r] - m);
        S[mt][nt][r] = p;
        sum += p;
      }
      sum += __shfl_xor(sum, 1);
      sum += __shfl_xor(sum, 2);
      sum += __shfl_xor(sum, 4);
      sum += __shfl_xor(sum, 8);
      float inv = 1.0f / sum;
      #pragma unroll
      for (int nt = 0; nt < 4; nt++) S[mt][nt][r] *= inv;
    }
  __syncthreads();  // everyone done reading Q/K before P overlays X+Q

  // ---- stage 4/5: P -> LDS, O = P @ V ----
  #pragma unroll
  for (int mt = 0; mt < 2; mt++)
    #pragma unroll
    for (int nt = 0; nt < 4; nt++)
      #pragma unroll
      for (int r = 0; r < 4; r++) {
        int row = 32 * mg + 16 * mt + 4 * lq + r;
        lds[P_OFF + sw(row, h * 64 + 16 * nt + ln16, 256)] = f2bf(S[mt][nt][r]);
      }
  __syncthreads();  // order P stores before P vector loads (and cross-wave safety)
  f32x4 O[2][2];
  O[0][0] = fz; O[0][1] = fz; O[1][0] = fz; O[1][1] = fz;
  #pragma unroll
  for (int ks = 0; ks < 2; ks++) {
    bf16x8 pf[2], vf[2];
    #pragma unroll
    for (int mt = 0; mt < 2; mt++)
      pf[mt] = *(const bf16x8_a*)(lds + P_OFF + sw(32 * mg + 16 * mt + ln16, h * 64 + 32 * ks + q8, 256));
    #pragma unroll
    for (int nt = 0; nt < 2; nt++)
      vf[nt] = *(const bf16x8_a*)(lds + VT_OFF + sw(h * 32 + 16 * nt + ln16, 32 * ks + q8, 64));
    #pragma unroll
    for (int mt = 0; mt < 2; mt++)
      #pragma unroll
      for (int nt = 0; nt < 2; nt++)
        O[mt][nt] = __builtin_amdgcn_mfma_f32_16x16x32_bf16(pf[mt], vf[nt], O[mt][nt], 0, 0, 0);
  }
  #pragma unroll
  for (int mt = 0; mt < 2; mt++)
    #pragma unroll
    for (int nt = 0; nt < 2; nt++)
      #pragma unroll
      for (int r = 0; r < 4; r++) {
        int row = 32 * mg + 16 * mt + 4 * lq + r;
        lds[AO_OFF + sw(row, h * 32 + 16 * nt + ln16, 128)] = f2bf(O[mt][nt][r]);
      }
  __syncthreads();

  // ---- stage 6: out = AO @ proj_w + proj_b ----
  f32x4 acc3[2][2];
  acc3[0][0] = fz; acc3[0][1] = fz; acc3[1][0] = fz; acc3[1][1] = fz;
  #pragma unroll
  for (int ks = 0; ks < 4; ks++) {
    bf16x8 a0 = *(const bf16x8_a*)(lds + AO_OFF + sw(32 * mg + ln16, 32 * ks + q8, 128));
    bf16x8 a1 = *(const bf16x8_a*)(lds + AO_OFF + sw(32 * mg + 16 + ln16, 32 * ks + q8, 128));
    bf16x8 b0 = *(const bf16x8_a*)(pwT + (32 * sub + ln16) * 128 + 32 * ks + q8);
    bf16x8 b1 = *(const bf16x8_a*)(pwT + (32 * sub + 16 + ln16) * 128 + 32 * ks + q8);
    acc3[0][0] = __builtin_amdgcn_mfma_f32_16x16x32_bf16(a0, b0, acc3[0][0], 0, 0, 0);
    acc3[0][1] = __builtin_amdgcn_mfma_f32_16x16x32_bf16(a0, b1, acc3[0][1], 0, 0, 0);
    acc3[1][0] = __builtin_amdgcn_mfma_f32_16x16x32_bf16(a1, b0, acc3[1][0], 0, 0, 0);
    acc3[1][1] = __builtin_amdgcn_mfma_f32_16x16x32_bf16(a1, b1, acc3[1][1], 0, 0, 0);
  }
  float pb0 = pbf[32 * sub + ln16];
  float pb1 = pbf[32 * sub + 16 + ln16];
  if (isbf) {
    u16* ob = (u16*)out;
    #pragma unroll
    for (int mt = 0; mt < 2; mt++)
      #pragma unroll
      for (int r = 0; r < 4; r++) {
        int row = 32 * mg + 16 * mt + 4 * lq + r;
        int o = xbase + (row >> 3) * 16384 + (row & 7) * 128 + 32 * sub;
        ob[o + ln16] = f2bf(acc3[mt][0][r] + pb0);
        ob[o + 16 + ln16] = f2bf(acc3[mt][1][r] + pb1);
      }
  } else {
    float* of = (float*)out;
    #pragma unroll
    for (int mt = 0; mt < 2; mt++)
      #pragma unroll
      for (int r = 0; r < 4; r++) {
        int row = 32 * mg + 16 * mt + 4 * lq + r;
        int o = xbase + (row >> 3) * 16384 + (row & 7) * 128 + 32 * sub;
        of[o + ln16] = acc3[mt][0][r] + pb0;
        of[o + 16 + ln16] = acc3[mt][1][r] + pb1;
      }
  }
}

extern "C" void kernel_launch(void* const* d_in, const int* in_sizes, int n_in,
                              void* d_out, int out_size, void* d_ws, size_t ws_size,
                              hipStream_t stream) {
  const void* x      = d_in[0];
  const void* mask   = d_in[1];
  const void* qkv_w  = d_in[2];
  const void* q_bias = d_in[3];
  const void* v_bias = d_in[4];
  const void* ls     = d_in[5];
  const void* cpb_w1 = d_in[6];
  const void* cpb_b1 = d_in[7];
  const void* cpb_w2 = d_in[8];
  const void* proj_w = d_in[9];
  const void* proj_b = d_in[10];
  const int B = in_sizes[0] / (128 * 128 * 128);

  char* ws = (char*)d_ws;
  swin_detect<<<1, 64, 0, stream>>>((const unsigned int*)x,
                                    (unsigned int*)(ws + FLAG_OFF));
  swin_setup<<<258, 256, 0, stream>>>(qkv_w, q_bias, v_bias, ls, cpb_w1, cpb_b1,
                                      cpb_w2, proj_w, proj_b, ws);
  swin_main<<<B * 256, 512, 0, stream>>>(x, mask, ws, d_out);
}